// Round 9
// baseline (117.876 us; speedup 1.0000x reference)
//
#include <hip/hip_runtime.h>

// TransformerBlockQuantum: [128, 8192, 8] fp32 in/out.
// R9: DS-pipe rebalance. GEMM1 stays MFMA; GEMM2 moves to 128 v_dot2/lane
// with SGPR weight pairs (W2P table). h relu+f16-packed token-major in hbuf
// (stride 20, conflict-free); each lane reads its own row once (4x b128).
// fbuf deleted; LN2 thread-local. DS insts/wave ~55 -> ~25.

#define NTOK   (128 * 8192)              // 1048576 tokens
#define NTHREADS 256
#define NBLOCKS  (NTOK / NTHREADS)       // 4096
#define LN_EPS 1e-5f
#define INV2PI 0.15915494309189535f

typedef __fp16 half2_t __attribute__((ext_vector_type(2)));
typedef __fp16 half8_t __attribute__((ext_vector_type(8)));
typedef float  float4_t __attribute__((ext_vector_type(4)));

union PK  { unsigned u; half2_t h; };
union U4H { uint4 u; half8_t h; half2_t h2[4]; unsigned w[4]; };

__device__ __forceinline__ float fast_cos_rev(float xrev) {
    return __builtin_amdgcn_cosf(xrev);        // v_cos_f32: revolutions in
}
__device__ __forceinline__ float fast_cos(float x) {
    return __builtin_amdgcn_cosf(x * INV2PI);
}
__device__ __forceinline__ float fast_rsqrt(float x) {
    return __builtin_amdgcn_rsqf(x);
}
__device__ __forceinline__ unsigned packh2(float a, float b) {
    PK c; c.h = __builtin_amdgcn_cvt_pkrtz(a, b); return c.u;
}
__device__ __forceinline__ float dot2(half2_t a, unsigned bw, float c) {
    PK b; b.u = bw;
    return __builtin_amdgcn_fdot2(a, b.h, c, false);
}

// ---- prep kernel ----------------------------------------------------------
// ws layout (uint32 words):
//   [0,32)    WqP[k][p]  = (Wq[2p][k], Wq[2p+1][k]) * INV2PI   (dot2 pairs)
//   [32,64)   WcP[kp][j] = (Wc[2kp][j], Wc[2kp+1][j])          (dot2 pairs)
//   [64,72)   qbias[k]   = (bq[k]+tha[k]) * INV2PI   (float bits)
//   [72,80)   cf[j]      = cos(theta_ffn[j])          (float bits)
//   [80,208)  W2P[c][j]  = (W2[c][j], W2[c+16][j])  c=0..15 j=0..7 (dot2 pairs)
//   [256,512) B1a frag:  uint4 per lane: W1[k][n0] f16 pairs (quad 0), else 0
//   [512,768) B1b frag:  same with n0+16
// Frag layout: A/B[m|n = lane&15][k = (lane>>4)*8 + j], pairs (2p,2p+1) along k.
__global__ void pack_weights(const float* __restrict__ Wq,
                             const float* __restrict__ W1,
                             const float* __restrict__ W2,
                             const float* __restrict__ Wc,
                             const float* __restrict__ bq,
                             const float* __restrict__ tha,
                             const float* __restrict__ thf,
                             unsigned* __restrict__ ws)
{
    int idx = threadIdx.x;
    if (idx < 32) {
        int k = idx >> 2, p = idx & 3;
        ws[idx] = packh2(Wq[(2 * p) * 8 + k] * INV2PI, Wq[(2 * p + 1) * 8 + k] * INV2PI);
    } else if (idx < 64) {
        int i2 = idx - 32;
        int kp = i2 >> 3, j = i2 & 7;
        ws[idx] = packh2(Wc[(2 * kp) * 8 + j], Wc[(2 * kp + 1) * 8 + j]);
    } else if (idx < 72) {
        int k = idx - 64;
        ws[idx] = __float_as_uint((bq[k] + tha[k]) * INV2PI);
    } else if (idx < 80) {
        int j = idx - 72;
        ws[idx] = __float_as_uint(__builtin_amdgcn_cosf(thf[j] * INV2PI));
    } else if (idx < 208) {
        int i2 = idx - 80;
        int c = i2 >> 3, j = i2 & 7;
        ws[idx] = packh2(W2[c * 8 + j], W2[(c + 16) * 8 + j]);
    } else if (idx >= 256 && idx < 384) {
        int t  = (idx - 256) & 63;          // lane id
        int tb = (idx - 256) >> 6;          // 0=B1a, 1=B1b
        int n0 = (t & 15) + tb * 16, q = t >> 4;
        unsigned r[4] = {0u, 0u, 0u, 0u};
        if (q == 0)
            for (int p = 0; p < 4; ++p)
                r[p] = packh2(W1[(2 * p) * 32 + n0], W1[(2 * p + 1) * 32 + n0]);
        uint4 w; w.x = r[0]; w.y = r[1]; w.z = r[2]; w.w = r[3];
        reinterpret_cast<uint4*>(ws)[64 + tb * 64 + t] = w;
    }
}

// ---- main kernel ----------------------------------------------------------
__global__ __launch_bounds__(NTHREADS, 6)
void qtb_kernel(const float* __restrict__ x,
                const float* __restrict__ bc,
                const float* __restrict__ g1,  const float* __restrict__ be1,
                const float* __restrict__ b1,
                const float* __restrict__ b2,
                const float* __restrict__ g2,  const float* __restrict__ be2,
                const unsigned* __restrict__ wp,
                float* __restrict__ out)
{
    const int tid  = threadIdx.x;
    const int wave = tid >> 6;
    const int lane = tid & 63;
    const int col  = lane & 15;
    const int quad = lane >> 4;
    const int g    = blockIdx.x * NTHREADS + tid;   // token id

    // ---- x load first: start HBM latency before everything else ----
    const float4* px = reinterpret_cast<const float4*>(x) + (size_t)g * 2;
    float4 xa = px[0];
    float4 xb = px[1];

    const float* qb = reinterpret_cast<const float*>(wp + 64);
    const float* cf = reinterpret_cast<const float*>(wp + 72);

    // wave-private LDS slices (no __syncthreads; same-wave lgkmcnt ordering)
    __shared__ uint4    zbuf[4][64];        // zf f16x8 per token        (4 KB)
    __shared__ unsigned hbuf[4][64 * 20];   // h f16 pairs (c,c+16), stride 20 (20 KB)

    // ---- MFMA weight fragments + bias C-inits (GEMM1 only) ----
    const uint4* fr = reinterpret_cast<const uint4*>(wp);
    U4H B1a, B1b;
    B1a.u = fr[64 + lane];
    B1b.u = fr[128 + lane];
    const float b1a_s = b1[col];
    const float b1b_s = b1[col + 16];

    float xv[8];
    half2_t xp[4];
    xv[0] = xa.x; xv[1] = xa.y; xv[2] = xa.z; xv[3] = xa.w;
    xv[4] = xb.x; xv[5] = xb.y; xv[6] = xb.z; xv[7] = xb.w;
    xp[0] = __builtin_amdgcn_cvt_pkrtz(xa.x, xa.y);
    xp[1] = __builtin_amdgcn_cvt_pkrtz(xa.z, xa.w);
    xp[2] = __builtin_amdgcn_cvt_pkrtz(xb.x, xb.y);
    xp[3] = __builtin_amdgcn_cvt_pkrtz(xb.z, xb.w);

    // ---- attention: q (revolutions) via dot2, cos, cumprods, z@Wc via dot2 ----
    float ca[8];
#pragma unroll
    for (int k = 0; k < 8; ++k) {
        float q = qb[k];
#pragma unroll
        for (int p = 0; p < 4; ++p) q = dot2(xp[p], wp[k * 4 + p], q);
        ca[k] = fast_cos_rev(q);
    }
    float attn[8];
#pragma unroll
    for (int j = 0; j < 8; ++j) attn[j] = bc[j];
    {
        float z[8];
        float cp  = ca[0];
        float cp1 = 1.0f;
#pragma unroll
        for (int k = 1; k < 8; ++k) {
            cp  *= ca[k];
            cp1 *= ca[k];
            z[k] = cp;
        }
        z[0] = cp1;
        half2_t zp[4];
#pragma unroll
        for (int p = 0; p < 4; ++p)
            zp[p] = __builtin_amdgcn_cvt_pkrtz(z[2 * p], z[2 * p + 1]);
#pragma unroll
        for (int p = 0; p < 4; ++p)
#pragma unroll
            for (int j = 0; j < 8; ++j)
                attn[j] = dot2(zp[p], wp[32 + p * 8 + j], attn[j]);
    }

    // ---- LN1 + zf = cf * cos(x1); keep x1 in xv ----
    {
        float y[8];
        float s = 0.f;
#pragma unroll
        for (int j = 0; j < 8; ++j) { y[j] = xv[j] + attn[j]; s += y[j]; }
        float m = s * 0.125f;
        float v = 0.f;
#pragma unroll
        for (int j = 0; j < 8; ++j) { float d = y[j] - m; v += d * d; }
        float r = fast_rsqrt(v * 0.125f + LN_EPS);
        float zf[8];
#pragma unroll
        for (int j = 0; j < 8; ++j) {
            float x1 = (y[j] - m) * r * g1[j] + be1[j];
            xv[j] = x1;
            zf[j] = cf[j] * fast_cos(x1);
        }
        U4H zpk;
#pragma unroll
        for (int p = 0; p < 4; ++p)
            zpk.h2[p] = __builtin_amdgcn_cvt_pkrtz(zf[2 * p], zf[2 * p + 1]);
        zbuf[wave][lane] = zpk.u;
    }

    // ---- GEMM1 on MFMA per 16-token group; h relu+f16 to token-major hbuf ----
#pragma unroll
    for (int grp = 0; grp < 4; ++grp) {
        // A1: zf of token (grp*16 + col), broadcast across quads (k>=8 of B is 0)
        U4H A1; A1.u = zbuf[wave][grp * 16 + col];
        float4_t c1a = {b1a_s, b1a_s, b1a_s, b1a_s};
        float4_t c1b = {b1b_s, b1b_s, b1b_s, b1b_s};
        float4_t h0 = __builtin_amdgcn_mfma_f32_16x16x32_f16(A1.h, B1a.h, c1a, 0, 0, 0);
        float4_t h1 = __builtin_amdgcn_mfma_f32_16x16x32_f16(A1.h, B1b.h, c1b, 0, 0, 0);
        // word[tok][c=col] = f16(relu(h[tok][col]), relu(h[tok][col+16])), row stride 20
#pragma unroll
        for (int r = 0; r < 4; ++r)
            hbuf[wave][(grp * 16 + 4 * quad + r) * 20 + col] =
                packh2(fmaxf(h0[r], 0.f), fmaxf(h1[r], 0.f));
    }

    // ---- GEMM2 on VALU: lane reads its own token's h row (16 words) once ----
    U4H hw[4];
    {
        const unsigned* hrow = &hbuf[wave][lane * 20];
#pragma unroll
        for (int c4 = 0; c4 < 4; ++c4)
            hw[c4].u = *reinterpret_cast<const uint4*>(hrow + 4 * c4);
    }
    float ffn[8];
#pragma unroll
    for (int j = 0; j < 8; ++j) ffn[j] = b2[j];
#pragma unroll
    for (int c = 0; c < 16; ++c) {
        half2_t hp = hw[c >> 2].h2[c & 3];   // feats (c, c+16)
#pragma unroll
        for (int j = 0; j < 8; ++j)
            ffn[j] = dot2(hp, wp[80 + c * 8 + j], ffn[j]);
    }

    // ---- LN2 (thread-local) + store ----
    {
        float y[8];
        float s = 0.f;
#pragma unroll
        for (int j = 0; j < 8; ++j) { y[j] = xv[j] + ffn[j]; s += y[j]; }
        float m = s * 0.125f;
        float v = 0.f;
#pragma unroll
        for (int j = 0; j < 8; ++j) { float d = y[j] - m; v += d * d; }
        float r = fast_rsqrt(v * 0.125f + LN_EPS);
        float o[8];
#pragma unroll
        for (int j = 0; j < 8; ++j) o[j] = (y[j] - m) * r * g2[j] + be2[j];
        float4* q = reinterpret_cast<float4*>(out) + (size_t)g * 2;
        q[0] = make_float4(o[0], o[1], o[2], o[3]);
        q[1] = make_float4(o[4], o[5], o[6], o[7]);
    }
}

extern "C" void kernel_launch(void* const* d_in, const int* in_sizes, int n_in,
                              void* d_out, int out_size, void* d_ws, size_t ws_size,
                              hipStream_t stream) {
    (void)in_sizes; (void)n_in; (void)ws_size; (void)out_size;
    unsigned* wp = (unsigned*)d_ws;
    pack_weights<<<1, 384, 0, stream>>>(
        (const float*)d_in[1],   // Wq
        (const float*)d_in[9],   // W1
        (const float*)d_in[11],  // W2
        (const float*)d_in[4],   // Wc
        (const float*)d_in[2],   // bq
        (const float*)d_in[3],   // theta_attn
        (const float*)d_in[8],   // theta_ffn
        wp);
    qtb_kernel<<<NBLOCKS, NTHREADS, 0, stream>>>(
        (const float*)d_in[0],  // x
        (const float*)d_in[5],  // bc
        (const float*)d_in[6],  // g1
        (const float*)d_in[7],  // beta1
        (const float*)d_in[10], // b1
        (const float*)d_in[12], // b2
        (const float*)d_in[13], // g2
        (const float*)d_in[14], // beta2
        wp,
        (float*)d_out);
}